// Round 1
// baseline (603.190 us; speedup 1.0000x reference)
//
#include <hip/hip_runtime.h>
#include <math.h>

#define NFEAT 50
#define NCLS 40

// ---- CSR build ------------------------------------------------------------

__global__ void k_count(const int* __restrict__ col, int E, int* __restrict__ cnt) {
    int e = blockIdx.x * blockDim.x + threadIdx.x;
    if (e < E) atomicAdd(&cnt[col[e]], 1);
}

__global__ void k_dis(const int* __restrict__ cnt, float* __restrict__ dis, int N) {
    int i = blockIdx.x * blockDim.x + threadIdx.x;
    if (i < N) dis[i] = rsqrtf((float)(cnt[i] + 1));  // +1 = self-loop; deg >= 1 always
}

// block-level exclusive scan (256 elems/block) + per-block totals
__global__ void k_scan_block(const int* __restrict__ cnt, int* __restrict__ offs,
                             int* __restrict__ bsum, int N) {
    __shared__ int s[256];
    int t = threadIdx.x;
    int i = blockIdx.x * 256 + t;
    int v = (i < N) ? cnt[i] : 0;
    s[t] = v;
    __syncthreads();
    for (int off = 1; off < 256; off <<= 1) {
        int a = (t >= off) ? s[t - off] : 0;
        __syncthreads();
        s[t] += a;
        __syncthreads();
    }
    if (i < N) offs[i] = s[t] - v;       // exclusive within block
    if (t == 255) bsum[blockIdx.x] = s[255];
}

__global__ void k_scan_sums(int* bsum, int nb) {
    if (blockIdx.x == 0 && threadIdx.x == 0) {
        int run = 0;
        for (int j = 0; j < nb; j++) { int tv = bsum[j]; bsum[j] = run; run += tv; }
    }
}

__global__ void k_apply(int* __restrict__ offs, int* __restrict__ cursor,
                        const int* __restrict__ bsum, int N) {
    int i = blockIdx.x * blockDim.x + threadIdx.x;
    if (i < N) {
        int base = offs[i] + bsum[i >> 8];
        offs[i] = base;
        cursor[i] = base;
    }
}

__global__ void k_scatter(const int* __restrict__ ei, int E,
                          int* __restrict__ cursor, int* __restrict__ rows) {
    int e = blockIdx.x * blockDim.x + threadIdx.x;
    if (e < E) {
        int r = ei[e];          // source
        int c = ei[E + e];      // target
        int p = atomicAdd(&cursor[c], 1);
        rows[p] = r;
    }
}

// ---- propagation: one wave per target node, lanes = features --------------

__global__ void k_prop(const float* __restrict__ hin, float* __restrict__ hout,
                       const float* __restrict__ dis, const int* __restrict__ offs,
                       const int* __restrict__ cnt, const int* __restrict__ rows, int N) {
    int wid = (blockIdx.x * blockDim.x + threadIdx.x) >> 6;
    int lane = threadIdx.x & 63;
    if (wid >= N) return;
    float dn = dis[wid];
    float acc = 0.f;
    if (lane < NFEAT) acc = dn * dn * hin[(size_t)wid * NFEAT + lane];  // self-loop
    int beg = offs[wid], num = cnt[wid];
    for (int j = 0; j < num; j++) {
        int r = rows[beg + j];            // wave-uniform load
        float w = dis[r] * dn;
        if (lane < NFEAT) acc += w * hin[(size_t)r * NFEAT + lane];
    }
    if (lane < NFEAT) hout[(size_t)wid * NFEAT + lane] = acc;
}

// ---- head: logits = h @ W + b, then log_softmax ---------------------------

__global__ void k_head(const float* __restrict__ h, const float* __restrict__ W,
                       const float* __restrict__ b, float* __restrict__ out, int N) {
    int n = blockIdx.x * blockDim.x + threadIdx.x;
    if (n >= N) return;
    float acc[NCLS];
    #pragma unroll
    for (int c = 0; c < NCLS; c++) acc[c] = b[c];
    for (int k = 0; k < NFEAT; k++) {
        float hk = h[(size_t)n * NFEAT + k];
        #pragma unroll
        for (int c = 0; c < NCLS; c++) acc[c] += hk * W[k * NCLS + c];  // W uniform -> scalar loads
    }
    float m = acc[0];
    #pragma unroll
    for (int c = 1; c < NCLS; c++) m = fmaxf(m, acc[c]);
    float s = 0.f;
    #pragma unroll
    for (int c = 0; c < NCLS; c++) s += __expf(acc[c] - m);
    float l = __logf(s) + m;
    #pragma unroll
    for (int c = 0; c < NCLS; c++) out[(size_t)n * NCLS + c] = acc[c] - l;
}

// ---- launcher -------------------------------------------------------------

extern "C" void kernel_launch(void* const* d_in, const int* in_sizes, int n_in,
                              void* d_out, int out_size, void* d_ws, size_t ws_size,
                              hipStream_t stream) {
    const float* x = (const float*)d_in[0];
    const int* ei = (const int*)d_in[1];   // [2, E] int32 (JAX default x64-off)
    const float* W = (const float*)d_in[2];
    const float* b = (const float*)d_in[3];
    float* out = (float*)d_out;

    int N = in_sizes[0] / NFEAT;
    int E = in_sizes[1] / 2;

    char* w = (char*)d_ws;
    auto alloc = [&](size_t bytes) { char* p = w; w += (bytes + 255) & ~(size_t)255; return p; };
    float* dis   = (float*)alloc((size_t)N * 4);
    int*  cnt    = (int*)  alloc((size_t)N * 4);
    int*  offs   = (int*)  alloc((size_t)N * 4);
    int*  cursor = (int*)  alloc((size_t)N * 4);
    int nb = (N + 255) / 256;
    int*  bsum   = (int*)  alloc((size_t)nb * 4);
    int*  rows   = (int*)  alloc((size_t)E * 4);
    float* h1    = (float*)alloc((size_t)N * NFEAT * 4);
    float* h2    = (float*)alloc((size_t)N * NFEAT * 4);

    hipMemsetAsync(cnt, 0, (size_t)N * 4, stream);

    int tE = (E + 255) / 256;
    k_count<<<tE, 256, 0, stream>>>(ei + E, E, cnt);
    k_dis<<<nb, 256, 0, stream>>>(cnt, dis, N);
    k_scan_block<<<nb, 256, 0, stream>>>(cnt, offs, bsum, N);
    k_scan_sums<<<1, 1, 0, stream>>>(bsum, nb);
    k_apply<<<nb, 256, 0, stream>>>(offs, cursor, bsum, N);
    k_scatter<<<tE, 256, 0, stream>>>(ei, E, cursor, rows);

    int pb = ((size_t)N * 64 + 255) / 256;
    k_prop<<<pb, 256, 0, stream>>>(x, h1, dis, offs, cnt, rows, N);
    k_prop<<<pb, 256, 0, stream>>>(h1, h2, dis, offs, cnt, rows, N);

    k_head<<<nb, 256, 0, stream>>>(h2, W, b, out, N);
}

// Round 2
// 381.665 us; speedup vs baseline: 1.5804x; 1.5804x over previous
//
#include <hip/hip_runtime.h>
#include <math.h>

#define NFEAT 50
#define NCLS 40

// ---- CSR build ------------------------------------------------------------

__global__ void k_count(const int* __restrict__ col, int E, int* __restrict__ cnt) {
    int e = blockIdx.x * blockDim.x + threadIdx.x;
    if (e < E) atomicAdd(&cnt[col[e]], 1);
}

// block-level exclusive scan (256 elems/block) + per-block totals
__global__ void k_scan_block(const int* __restrict__ cnt, int* __restrict__ offs,
                             int* __restrict__ bsum, int N) {
    __shared__ int s[256];
    int t = threadIdx.x;
    int i = blockIdx.x * 256 + t;
    int v = (i < N) ? cnt[i] : 0;
    s[t] = v;
    __syncthreads();
    for (int off = 1; off < 256; off <<= 1) {
        int a = (t >= off) ? s[t - off] : 0;
        __syncthreads();
        s[t] += a;
        __syncthreads();
    }
    if (i < N) offs[i] = s[t] - v;       // exclusive within block
    if (t == 255) bsum[blockIdx.x] = s[255];
}

// one-block parallel exclusive scan over block sums (chunks of 512 with carry)
__global__ void k_scan_sums(int* __restrict__ bsum, int nb) {
    __shared__ int s[512];
    __shared__ int carry;
    int t = threadIdx.x;
    if (t == 0) carry = 0;
    __syncthreads();
    for (int base = 0; base < nb; base += 512) {
        int i = base + t;
        int v = (i < nb) ? bsum[i] : 0;
        s[t] = v;
        __syncthreads();
        for (int off = 1; off < 512; off <<= 1) {
            int a = (t >= off) ? s[t - off] : 0;
            __syncthreads();
            s[t] += a;
            __syncthreads();
        }
        int incl = s[t];
        int tot = s[511];
        int c = carry;
        if (i < nb) bsum[i] = c + incl - v;   // exclusive + carry
        __syncthreads();
        if (t == 0) carry = c + tot;
        __syncthreads();
    }
}

// dis = rsqrt(deg+1); offs/cursor = scanned base (fused k_dis + k_apply)
__global__ void k_apply(int* __restrict__ offs, int* __restrict__ cursor,
                        const int* __restrict__ bsum, const int* __restrict__ cnt,
                        float* __restrict__ dis, int N) {
    int i = blockIdx.x * blockDim.x + threadIdx.x;
    if (i < N) {
        int base = offs[i] + bsum[i >> 8];
        offs[i] = base;
        cursor[i] = base;
        dis[i] = rsqrtf((float)(cnt[i] + 1));
    }
}

__global__ void k_scatter(const int* __restrict__ ei, int E,
                          int* __restrict__ cursor, int* __restrict__ rows) {
    int e = blockIdx.x * blockDim.x + threadIdx.x;
    if (e < E) {
        int r = ei[e];          // source
        int c = ei[E + e];      // target
        int p = atomicAdd(&cursor[c], 1);
        rows[p] = r;
    }
}

// ---- propagation: one wave per target node, lanes = features --------------
// hout[wid] = dn * ( dn*hin[wid] + sum_j dis[r_j]*hin[r_j] )

__global__ void k_prop(const float* __restrict__ hin, float* __restrict__ hout,
                       const float* __restrict__ dis, const int* __restrict__ offs,
                       const int* __restrict__ cnt, const int* __restrict__ rows, int N) {
    int wid = (blockIdx.x * blockDim.x + threadIdx.x) >> 6;
    int lane = threadIdx.x & 63;
    if (wid >= N) return;
    float dn = dis[wid];
    int beg = offs[wid], num = cnt[wid];

    float acc = 0.f;
    if (lane < NFEAT) acc = dn * hin[(size_t)wid * NFEAT + lane];  // self-loop (pre dn factor)

    int j = 0;
    for (; j + 4 <= num; j += 4) {
        // 4 independent gather chains in flight
        int r0 = rows[beg + j + 0];
        int r1 = rows[beg + j + 1];
        int r2 = rows[beg + j + 2];
        int r3 = rows[beg + j + 3];
        float w0 = dis[r0], w1 = dis[r1], w2 = dis[r2], w3 = dis[r3];
        float v0 = 0.f, v1 = 0.f, v2 = 0.f, v3 = 0.f;
        if (lane < NFEAT) {
            v0 = hin[(size_t)r0 * NFEAT + lane];
            v1 = hin[(size_t)r1 * NFEAT + lane];
            v2 = hin[(size_t)r2 * NFEAT + lane];
            v3 = hin[(size_t)r3 * NFEAT + lane];
        }
        acc += w0 * v0;
        acc += w1 * v1;
        acc += w2 * v2;
        acc += w3 * v3;
    }
    for (; j < num; j++) {
        int r = rows[beg + j];
        float v = (lane < NFEAT) ? hin[(size_t)r * NFEAT + lane] : 0.f;
        acc += dis[r] * v;
    }
    if (lane < NFEAT) hout[(size_t)wid * NFEAT + lane] = acc * dn;
}

// ---- head: logits = h @ W + b, then log_softmax ---------------------------

__global__ void k_head(const float* __restrict__ h, const float* __restrict__ W,
                       const float* __restrict__ b, float* __restrict__ out, int N) {
    int n = blockIdx.x * blockDim.x + threadIdx.x;
    if (n >= N) return;
    float acc[NCLS];
    #pragma unroll
    for (int c = 0; c < NCLS; c++) acc[c] = b[c];
    for (int k = 0; k < NFEAT; k++) {
        float hk = h[(size_t)n * NFEAT + k];
        #pragma unroll
        for (int c = 0; c < NCLS; c++) acc[c] += hk * W[k * NCLS + c];  // W uniform -> scalar cached
    }
    float m = acc[0];
    #pragma unroll
    for (int c = 1; c < NCLS; c++) m = fmaxf(m, acc[c]);
    float s = 0.f;
    #pragma unroll
    for (int c = 0; c < NCLS; c++) s += __expf(acc[c] - m);
    float l = __logf(s) + m;
    #pragma unroll
    for (int c = 0; c < NCLS; c++) out[(size_t)n * NCLS + c] = acc[c] - l;
}

// ---- launcher -------------------------------------------------------------

extern "C" void kernel_launch(void* const* d_in, const int* in_sizes, int n_in,
                              void* d_out, int out_size, void* d_ws, size_t ws_size,
                              hipStream_t stream) {
    const float* x = (const float*)d_in[0];
    const int* ei = (const int*)d_in[1];   // [2, E] int32 (JAX default x64-off)
    const float* W = (const float*)d_in[2];
    const float* b = (const float*)d_in[3];
    float* out = (float*)d_out;

    int N = in_sizes[0] / NFEAT;
    int E = in_sizes[1] / 2;

    char* w = (char*)d_ws;
    auto alloc = [&](size_t bytes) { char* p = w; w += (bytes + 255) & ~(size_t)255; return p; };
    float* dis   = (float*)alloc((size_t)N * 4);
    int*  cnt    = (int*)  alloc((size_t)N * 4);
    int*  offs   = (int*)  alloc((size_t)N * 4);
    int*  cursor = (int*)  alloc((size_t)N * 4);
    int nb = (N + 255) / 256;
    int*  bsum   = (int*)  alloc((size_t)nb * 4);
    int*  rows   = (int*)  alloc((size_t)E * 4);
    float* h1    = (float*)alloc((size_t)N * NFEAT * 4);
    float* h2    = (float*)alloc((size_t)N * NFEAT * 4);

    hipMemsetAsync(cnt, 0, (size_t)N * 4, stream);

    int tE = (E + 255) / 256;
    k_count<<<tE, 256, 0, stream>>>(ei + E, E, cnt);
    k_scan_block<<<nb, 256, 0, stream>>>(cnt, offs, bsum, N);
    k_scan_sums<<<1, 512, 0, stream>>>(bsum, nb);
    k_apply<<<nb, 256, 0, stream>>>(offs, cursor, bsum, cnt, dis, N);
    k_scatter<<<tE, 256, 0, stream>>>(ei, E, cursor, rows);

    int pb = (int)(((size_t)N * 64 + 255) / 256);
    k_prop<<<pb, 256, 0, stream>>>(x, h1, dis, offs, cnt, rows, N);
    k_prop<<<pb, 256, 0, stream>>>(h1, h2, dis, offs, cnt, rows, N);

    k_head<<<nb, 256, 0, stream>>>(h2, W, b, out, N);
}

// Round 3
// 201.916 us; speedup vs baseline: 2.9873x; 1.8902x over previous
//
#include <hip/hip_runtime.h>
#include <math.h>

#define NFEAT 50
#define NCLS 40
#define TPBK 256          // targets per bucket (power of 2)
#define TPBK_SHIFT 8
#define EPB 4096          // edges per partition block
#define MAXNB 512         // max buckets supported by single-block scan

__device__ __forceinline__ float bf2f(unsigned short u) {
    return __uint_as_float(((unsigned)u) << 16);
}
__device__ __forceinline__ unsigned short f2bf(float f) {
    unsigned u = __float_as_uint(f);
    unsigned r = (u + 0x7FFFu + ((u >> 16) & 1u)) >> 16;   // round-nearest-even
    return (unsigned short)r;
}

// ---- 1. bucket histogram over targets -------------------------------------

__global__ void k_bhist(const int* __restrict__ col, int E, int* __restrict__ bhist, int NB) {
    __shared__ int h[MAXNB];
    for (int i = threadIdx.x; i < NB; i += blockDim.x) h[i] = 0;
    __syncthreads();
    int i0 = blockIdx.x * EPB;
    #pragma unroll
    for (int k = 0; k < EPB / 256; k++) {
        int e = i0 + k * 256 + threadIdx.x;
        if (e < E) atomicAdd(&h[col[e] >> TPBK_SHIFT], 1);
    }
    __syncthreads();
    for (int i = threadIdx.x; i < NB; i += blockDim.x)
        if (h[i]) atomicAdd(&bhist[i], h[i]);
}

// ---- 2. scan bucket bases (single block) ----------------------------------

__global__ void k_bscan(const int* __restrict__ bhist, int* __restrict__ bbase,
                        int* __restrict__ gcur, int NB) {
    __shared__ int s[MAXNB];
    int t = threadIdx.x;
    int v = (t < NB) ? bhist[t] : 0;
    s[t] = v;
    __syncthreads();
    for (int off = 1; off < MAXNB; off <<= 1) {
        int a = (t >= off) ? s[t - off] : 0;
        __syncthreads();
        s[t] += a;
        __syncthreads();
    }
    if (t < NB) { int b = s[t] - v; bbase[t] = b; gcur[t] = b; }
}

// ---- 3. partition edges into bucket-contiguous (r,c) pairs ----------------

__global__ void k_part(const int* __restrict__ ei, int E, int* __restrict__ gcur,
                       int2* __restrict__ pairs, int NB) {
    __shared__ int h[MAXNB];
    __shared__ int base[MAXNB];
    for (int i = threadIdx.x; i < NB; i += 256) h[i] = 0;
    __syncthreads();
    int i0 = blockIdx.x * EPB;
    int r[16], c[16];
    #pragma unroll
    for (int k = 0; k < 16; k++) {
        int e = i0 + k * 256 + threadIdx.x;
        if (e < E) {
            r[k] = ei[e];
            c[k] = ei[E + e];
            atomicAdd(&h[c[k] >> TPBK_SHIFT], 1);
        } else c[k] = -1;
    }
    __syncthreads();
    for (int i = threadIdx.x; i < NB; i += 256)
        base[i] = h[i] ? atomicAdd(&gcur[i], h[i]) : 0;
    __syncthreads();
    for (int i = threadIdx.x; i < NB; i += 256) h[i] = 0;
    __syncthreads();
    #pragma unroll
    for (int k = 0; k < 16; k++) {
        if (c[k] >= 0) {
            int bkt = c[k] >> TPBK_SHIFT;
            int p = base[bkt] + atomicAdd(&h[bkt], 1);
            pairs[p] = make_int2(r[k], c[k]);
        }
    }
}

// ---- 4. per-bucket CSR finalize: cnt/offs/dis/rows ------------------------

__global__ void k_bucket(const int2* __restrict__ pairs, const int* __restrict__ bbase,
                         const int* __restrict__ bhist, int* __restrict__ rows,
                         int* __restrict__ cnt, int* __restrict__ offs,
                         float* __restrict__ dis, int N) {
    int b = blockIdx.x;
    int ebeg = bbase[b], m = bhist[b];
    int t0 = b << TPBK_SHIFT;
    __shared__ int h[TPBK];
    __shared__ int off[TPBK];
    int t = threadIdx.x;       // 256 threads
    h[t] = 0;
    __syncthreads();
    for (int i = t; i < m; i += 256) atomicAdd(&h[pairs[ebeg + i].y - t0], 1);
    __syncthreads();
    int v = h[t];
    off[t] = v;
    __syncthreads();
    for (int o = 1; o < TPBK; o <<= 1) {
        int a = (t >= o) ? off[t - o] : 0;
        __syncthreads();
        off[t] += a;
        __syncthreads();
    }
    int excl = off[t] - v;
    int tg = t0 + t;
    if (tg < N) {
        cnt[tg] = v;
        offs[tg] = ebeg + excl;
        dis[tg] = rsqrtf((float)(v + 1));
    }
    __syncthreads();
    off[t] = excl;
    h[t] = 0;
    __syncthreads();
    for (int i = t; i < m; i += 256) {
        int2 p = pairs[ebeg + i];
        int lt = p.y - t0;
        int pos = off[lt] + atomicAdd(&h[lt], 1);
        rows[ebeg + pos] = p.x;
    }
}

// ---- 5. convert x -> z0 = dis * x, bf16, padded stride 64 -----------------

__global__ void k_cvt(const float* __restrict__ x, const float* __restrict__ dis,
                      unsigned short* __restrict__ xb, int N) {
    int i = blockIdx.x * 256 + threadIdx.x;
    int n = i >> 6, f = i & 63;
    if (n >= N) return;
    float v = (f < NFEAT) ? x[(size_t)n * NFEAT + f] * dis[n] : 0.f;
    xb[i] = f2bf(v);
}

// ---- 6. propagation: z_out[c] = dis[c]^2 * (z[c] + sum z[r]) --------------

__global__ void k_prop(const unsigned short* __restrict__ zin, unsigned short* __restrict__ zout,
                       const float* __restrict__ dis, const int* __restrict__ offs,
                       const int* __restrict__ cnt, const int* __restrict__ rows, int N) {
    int wid = (blockIdx.x * blockDim.x + threadIdx.x) >> 6;
    int lane = threadIdx.x & 63;
    if (wid >= N) return;
    int beg = offs[wid], num = cnt[wid];
    float acc = bf2f(zin[((size_t)wid << 6) + lane]);   // self-loop term
    int j = 0;
    for (; j + 8 <= num; j += 8) {
        int r0 = rows[beg + j + 0], r1 = rows[beg + j + 1];
        int r2 = rows[beg + j + 2], r3 = rows[beg + j + 3];
        int r4 = rows[beg + j + 4], r5 = rows[beg + j + 5];
        int r6 = rows[beg + j + 6], r7 = rows[beg + j + 7];
        float v0 = bf2f(zin[((size_t)r0 << 6) + lane]);
        float v1 = bf2f(zin[((size_t)r1 << 6) + lane]);
        float v2 = bf2f(zin[((size_t)r2 << 6) + lane]);
        float v3 = bf2f(zin[((size_t)r3 << 6) + lane]);
        float v4 = bf2f(zin[((size_t)r4 << 6) + lane]);
        float v5 = bf2f(zin[((size_t)r5 << 6) + lane]);
        float v6 = bf2f(zin[((size_t)r6 << 6) + lane]);
        float v7 = bf2f(zin[((size_t)r7 << 6) + lane]);
        acc += ((v0 + v1) + (v2 + v3)) + ((v4 + v5) + (v6 + v7));
    }
    for (; j + 4 <= num; j += 4) {
        int r0 = rows[beg + j + 0], r1 = rows[beg + j + 1];
        int r2 = rows[beg + j + 2], r3 = rows[beg + j + 3];
        float v0 = bf2f(zin[((size_t)r0 << 6) + lane]);
        float v1 = bf2f(zin[((size_t)r1 << 6) + lane]);
        float v2 = bf2f(zin[((size_t)r2 << 6) + lane]);
        float v3 = bf2f(zin[((size_t)r3 << 6) + lane]);
        acc += (v0 + v1) + (v2 + v3);
    }
    for (; j < num; j++) {
        int r = rows[beg + j];
        acc += bf2f(zin[((size_t)r << 6) + lane]);
    }
    float dn = dis[wid];
    zout[((size_t)wid << 6) + lane] = f2bf(acc * dn * dn);
}

// ---- 7. head: h = z / dis; logits = h @ W + b; log_softmax ----------------

__global__ void k_head(const unsigned short* __restrict__ z2, const int* __restrict__ cnt,
                       const float* __restrict__ W, const float* __restrict__ b,
                       float* __restrict__ out, int N) {
    int n = blockIdx.x * blockDim.x + threadIdx.x;
    if (n >= N) return;
    float s = sqrtf((float)(cnt[n] + 1));   // 1/dis
    float acc[NCLS];
    #pragma unroll
    for (int c = 0; c < NCLS; c++) acc[c] = b[c];
    for (int k = 0; k < NFEAT; k++) {
        float hk = bf2f(z2[((size_t)n << 6) + k]) * s;
        #pragma unroll
        for (int c = 0; c < NCLS; c++) acc[c] += hk * W[k * NCLS + c];
    }
    float m = acc[0];
    #pragma unroll
    for (int c = 1; c < NCLS; c++) m = fmaxf(m, acc[c]);
    float sum = 0.f;
    #pragma unroll
    for (int c = 0; c < NCLS; c++) sum += __expf(acc[c] - m);
    float l = __logf(sum) + m;
    #pragma unroll
    for (int c = 0; c < NCLS; c++) out[(size_t)n * NCLS + c] = acc[c] - l;
}

// ---- launcher -------------------------------------------------------------

extern "C" void kernel_launch(void* const* d_in, const int* in_sizes, int n_in,
                              void* d_out, int out_size, void* d_ws, size_t ws_size,
                              hipStream_t stream) {
    const float* x = (const float*)d_in[0];
    const int* ei = (const int*)d_in[1];   // [2, E] int32
    const float* W = (const float*)d_in[2];
    const float* b = (const float*)d_in[3];
    float* out = (float*)d_out;

    int N = in_sizes[0] / NFEAT;
    int E = in_sizes[1] / 2;
    int NB = (N + TPBK - 1) / TPBK;        // 391 buckets

    char* w = (char*)d_ws;
    auto alloc = [&](size_t bytes) { char* p = w; w += (bytes + 255) & ~(size_t)255; return p; };
    int*   bhist = (int*)  alloc((size_t)NB * 4);
    int*   bbase = (int*)  alloc((size_t)NB * 4);
    int*   gcur  = (int*)  alloc((size_t)NB * 4);
    int*   cnt   = (int*)  alloc((size_t)N * 4);
    int*   offs  = (int*)  alloc((size_t)N * 4);
    float* dis   = (float*)alloc((size_t)N * 4);
    int*   rows  = (int*)  alloc((size_t)E * 4);
    unsigned short* xb = (unsigned short*)alloc((size_t)N * 64 * 2);
    unsigned short* z1 = (unsigned short*)alloc((size_t)N * 64 * 2);
    // pairs and z2 are disjoint in time: pairs dead after k_bucket, z2 born at 2nd k_prop
    char* uni = alloc((size_t)E * 8 > (size_t)N * 64 * 2 ? (size_t)E * 8 : (size_t)N * 64 * 2);
    int2* pairs = (int2*)uni;
    unsigned short* z2 = (unsigned short*)uni;

    hipMemsetAsync(bhist, 0, (size_t)NB * 4, stream);

    int pe = (E + EPB - 1) / EPB;          // 391 partition blocks
    k_bhist<<<pe, 256, 0, stream>>>(ei + E, E, bhist, NB);
    k_bscan<<<1, MAXNB, 0, stream>>>(bhist, bbase, gcur, NB);
    k_part<<<pe, 256, 0, stream>>>(ei, E, gcur, pairs, NB);
    k_bucket<<<NB, TPBK, 0, stream>>>(pairs, bbase, bhist, rows, cnt, offs, dis, N);

    k_cvt<<<(int)(((size_t)N * 64 + 255) / 256), 256, 0, stream>>>(x, dis, xb, N);

    int pb = (int)(((size_t)N * 64 + 255) / 256);
    k_prop<<<pb, 256, 0, stream>>>(xb, z1, dis, offs, cnt, rows, N);
    k_prop<<<pb, 256, 0, stream>>>(z1, z2, dis, offs, cnt, rows, N);

    k_head<<<(N + 255) / 256, 256, 0, stream>>>(z2, cnt, W, b, out, N);
}

// Round 4
// 187.389 us; speedup vs baseline: 3.2189x; 1.0775x over previous
//
#include <hip/hip_runtime.h>
#include <math.h>

#define NFEAT 50
#define NCLS 40
#define TPBK 256          // targets per bucket (power of 2)
#define TPBK_SHIFT 8
#define EPB 4096          // edges per partition block
#define MAXNB 512         // max buckets supported by single-block scan

__device__ __forceinline__ float bf2f(unsigned short u) {
    return __uint_as_float(((unsigned)u) << 16);
}
__device__ __forceinline__ unsigned short f2bf(float f) {
    unsigned u = __float_as_uint(f);
    unsigned r = (u + 0x7FFFu + ((u >> 16) & 1u)) >> 16;   // round-nearest-even
    return (unsigned short)r;
}

// ---- 1. bucket histogram over targets -------------------------------------

__global__ void k_bhist(const int* __restrict__ col, int E, int* __restrict__ bhist, int NB) {
    __shared__ int h[MAXNB];
    for (int i = threadIdx.x; i < NB; i += blockDim.x) h[i] = 0;
    __syncthreads();
    int i0 = blockIdx.x * EPB;
    #pragma unroll
    for (int k = 0; k < EPB / 256; k++) {
        int e = i0 + k * 256 + threadIdx.x;
        if (e < E) atomicAdd(&h[col[e] >> TPBK_SHIFT], 1);
    }
    __syncthreads();
    for (int i = threadIdx.x; i < NB; i += blockDim.x)
        if (h[i]) atomicAdd(&bhist[i], h[i]);
}

// ---- 2. scan bucket bases (single block) ----------------------------------

__global__ void k_bscan(const int* __restrict__ bhist, int* __restrict__ bbase,
                        int* __restrict__ gcur, int NB) {
    __shared__ int s[MAXNB];
    int t = threadIdx.x;
    int v = (t < NB) ? bhist[t] : 0;
    s[t] = v;
    __syncthreads();
    for (int off = 1; off < MAXNB; off <<= 1) {
        int a = (t >= off) ? s[t - off] : 0;
        __syncthreads();
        s[t] += a;
        __syncthreads();
    }
    if (t < NB) { int b = s[t] - v; bbase[t] = b; gcur[t] = b; }
}

// ---- 3. partition edges into bucket-contiguous (r,c) pairs ----------------

__global__ void k_part(const int* __restrict__ ei, int E, int* __restrict__ gcur,
                       int2* __restrict__ pairs, int NB) {
    __shared__ int h[MAXNB];
    __shared__ int base[MAXNB];
    for (int i = threadIdx.x; i < NB; i += 256) h[i] = 0;
    __syncthreads();
    int i0 = blockIdx.x * EPB;
    int r[16], c[16];
    #pragma unroll
    for (int k = 0; k < 16; k++) {
        int e = i0 + k * 256 + threadIdx.x;
        if (e < E) {
            r[k] = ei[e];
            c[k] = ei[E + e];
            atomicAdd(&h[c[k] >> TPBK_SHIFT], 1);
        } else c[k] = -1;
    }
    __syncthreads();
    for (int i = threadIdx.x; i < NB; i += 256)
        base[i] = h[i] ? atomicAdd(&gcur[i], h[i]) : 0;
    __syncthreads();
    for (int i = threadIdx.x; i < NB; i += 256) h[i] = 0;
    __syncthreads();
    #pragma unroll
    for (int k = 0; k < 16; k++) {
        if (c[k] >= 0) {
            int bkt = c[k] >> TPBK_SHIFT;
            int p = base[bkt] + atomicAdd(&h[bkt], 1);
            pairs[p] = make_int2(r[k], c[k]);
        }
    }
}

// ---- 4. per-bucket CSR finalize + fused x->z0 conversion ------------------

__global__ void k_bucket(const int2* __restrict__ pairs, const int* __restrict__ bbase,
                         const int* __restrict__ bhist, int* __restrict__ rows,
                         int* __restrict__ cnt, int* __restrict__ offs,
                         float* __restrict__ dis, const float* __restrict__ x,
                         unsigned short* __restrict__ xb, int N) {
    int b = blockIdx.x;
    int ebeg = bbase[b], m = bhist[b];
    int t0 = b << TPBK_SHIFT;
    __shared__ int h[TPBK];
    __shared__ int off[TPBK];
    __shared__ float diss[TPBK];
    int t = threadIdx.x;       // 256 threads
    h[t] = 0;
    __syncthreads();
    for (int i = t; i < m; i += 256) atomicAdd(&h[pairs[ebeg + i].y - t0], 1);
    __syncthreads();
    int v = h[t];
    off[t] = v;
    __syncthreads();
    for (int o = 1; o < TPBK; o <<= 1) {
        int a = (t >= o) ? off[t - o] : 0;
        __syncthreads();
        off[t] += a;
        __syncthreads();
    }
    int excl = off[t] - v;
    int tg = t0 + t;
    float d = rsqrtf((float)(v + 1));
    diss[t] = d;
    if (tg < N) {
        cnt[tg] = v;
        offs[tg] = ebeg + excl;
        dis[tg] = d;
    }
    __syncthreads();
    off[t] = excl;
    h[t] = 0;
    __syncthreads();
    for (int i = t; i < m; i += 256) {
        int2 p = pairs[ebeg + i];
        int lt = p.y - t0;
        int pos = off[lt] + atomicAdd(&h[lt], 1);
        rows[ebeg + pos] = p.x;
    }
    // fused conversion: xb[n] = f2bf(dis[n] * x[n]) for this block's 256 nodes
    int nmax = N - t0; if (nmax > TPBK) nmax = TPBK;
    for (int idx = t; idx < (nmax << 6); idx += 256) {
        int nl = idx >> 6, f = idx & 63;
        int n = t0 + nl;
        float val = (f < NFEAT) ? x[(size_t)n * NFEAT + f] * diss[nl] : 0.f;
        xb[((size_t)n << 6) + f] = f2bf(val);
    }
}

// ---- 5. propagation: z_out[c] = dis[c]^2 * (z[c] + sum z[r]) --------------
// wave per target; 4 lane-groups of 16; each lane carries 4 features (ushort4).
// One gather instruction fetches 4 edges x 128B.

__global__ void k_prop(const unsigned short* __restrict__ zin, unsigned short* __restrict__ zout,
                       const float* __restrict__ dis, const int* __restrict__ offs,
                       const int* __restrict__ cnt, const int* __restrict__ rows, int N) {
    int wid = (blockIdx.x * blockDim.x + threadIdx.x) >> 6;
    int lane = threadIdx.x & 63;
    if (wid >= N) return;
    int g = lane >> 4;            // edge subgroup 0..3
    int fl = (lane & 15) << 2;    // feature base 0,4,...,60
    int beg = offs[wid], num = cnt[wid];

    float a0 = 0.f, a1 = 0.f, a2 = 0.f, a3 = 0.f;
    if (g == 0) {                 // self-loop term counted once
        ushort4 s = *(const ushort4*)&zin[((size_t)wid << 6) + fl];
        a0 = bf2f(s.x); a1 = bf2f(s.y); a2 = bf2f(s.z); a3 = bf2f(s.w);
    }

    for (int j = 0; j < num; j += 16) {
        int i0 = j + (g << 2);    // this group's 4 edges: i0..i0+3
        int e0 = i0, e1 = i0 + 1, e2 = i0 + 2, e3 = i0 + 3;
        float m0 = e0 < num ? 1.f : 0.f;
        float m1 = e1 < num ? 1.f : 0.f;
        float m2 = e2 < num ? 1.f : 0.f;
        float m3 = e3 < num ? 1.f : 0.f;
        int c0 = e0 < num ? e0 : num - 1;
        int c1 = e1 < num ? e1 : num - 1;
        int c2 = e2 < num ? e2 : num - 1;
        int c3 = e3 < num ? e3 : num - 1;
        int r0 = rows[beg + c0];
        int r1 = rows[beg + c1];
        int r2 = rows[beg + c2];
        int r3 = rows[beg + c3];
        ushort4 v0 = *(const ushort4*)&zin[((size_t)r0 << 6) + fl];
        ushort4 v1 = *(const ushort4*)&zin[((size_t)r1 << 6) + fl];
        ushort4 v2 = *(const ushort4*)&zin[((size_t)r2 << 6) + fl];
        ushort4 v3 = *(const ushort4*)&zin[((size_t)r3 << 6) + fl];
        a0 = fmaf(m0, bf2f(v0.x), a0); a1 = fmaf(m0, bf2f(v0.y), a1);
        a2 = fmaf(m0, bf2f(v0.z), a2); a3 = fmaf(m0, bf2f(v0.w), a3);
        a0 = fmaf(m1, bf2f(v1.x), a0); a1 = fmaf(m1, bf2f(v1.y), a1);
        a2 = fmaf(m1, bf2f(v1.z), a2); a3 = fmaf(m1, bf2f(v1.w), a3);
        a0 = fmaf(m2, bf2f(v2.x), a0); a1 = fmaf(m2, bf2f(v2.y), a1);
        a2 = fmaf(m2, bf2f(v2.z), a2); a3 = fmaf(m2, bf2f(v2.w), a3);
        a0 = fmaf(m3, bf2f(v3.x), a0); a1 = fmaf(m3, bf2f(v3.y), a1);
        a2 = fmaf(m3, bf2f(v3.z), a2); a3 = fmaf(m3, bf2f(v3.w), a3);
    }

    // reduce across the 4 groups (lanes l, l+16, l+32, l+48 hold same features)
    a0 += __shfl_xor(a0, 16); a0 += __shfl_xor(a0, 32);
    a1 += __shfl_xor(a1, 16); a1 += __shfl_xor(a1, 32);
    a2 += __shfl_xor(a2, 16); a2 += __shfl_xor(a2, 32);
    a3 += __shfl_xor(a3, 16); a3 += __shfl_xor(a3, 32);

    float dn = dis[wid];
    float s2 = dn * dn;
    if (lane < 16) {
        ushort4 o;
        o.x = f2bf(a0 * s2); o.y = f2bf(a1 * s2);
        o.z = f2bf(a2 * s2); o.w = f2bf(a3 * s2);
        *(ushort4*)&zout[((size_t)wid << 6) + fl] = o;
    }
}

// ---- 6. head: h = z / dis; logits = h @ W + b; log_softmax ----------------

__global__ void k_head(const unsigned short* __restrict__ z2, const int* __restrict__ cnt,
                       const float* __restrict__ W, const float* __restrict__ b,
                       float* __restrict__ out, int N) {
    int n = blockIdx.x * blockDim.x + threadIdx.x;
    if (n >= N) return;
    float s = sqrtf((float)(cnt[n] + 1));   // 1/dis
    float acc[NCLS];
    #pragma unroll
    for (int c = 0; c < NCLS; c++) acc[c] = b[c];
    for (int k = 0; k < NFEAT; k++) {
        float hk = bf2f(z2[((size_t)n << 6) + k]) * s;
        #pragma unroll
        for (int c = 0; c < NCLS; c++) acc[c] += hk * W[k * NCLS + c];
    }
    float m = acc[0];
    #pragma unroll
    for (int c = 1; c < NCLS; c++) m = fmaxf(m, acc[c]);
    float sum = 0.f;
    #pragma unroll
    for (int c = 0; c < NCLS; c++) sum += __expf(acc[c] - m);
    float l = __logf(sum) + m;
    #pragma unroll
    for (int c = 0; c < NCLS; c++) out[(size_t)n * NCLS + c] = acc[c] - l;
}

// ---- launcher -------------------------------------------------------------

extern "C" void kernel_launch(void* const* d_in, const int* in_sizes, int n_in,
                              void* d_out, int out_size, void* d_ws, size_t ws_size,
                              hipStream_t stream) {
    const float* x = (const float*)d_in[0];
    const int* ei = (const int*)d_in[1];   // [2, E] int32
    const float* W = (const float*)d_in[2];
    const float* b = (const float*)d_in[3];
    float* out = (float*)d_out;

    int N = in_sizes[0] / NFEAT;
    int E = in_sizes[1] / 2;
    int NB = (N + TPBK - 1) / TPBK;        // 391 buckets

    char* w = (char*)d_ws;
    auto alloc = [&](size_t bytes) { char* p = w; w += (bytes + 255) & ~(size_t)255; return p; };
    int*   bhist = (int*)  alloc((size_t)NB * 4);
    int*   bbase = (int*)  alloc((size_t)NB * 4);
    int*   gcur  = (int*)  alloc((size_t)NB * 4);
    int*   cnt   = (int*)  alloc((size_t)N * 4);
    int*   offs  = (int*)  alloc((size_t)N * 4);
    float* dis   = (float*)alloc((size_t)N * 4);
    int*   rows  = (int*)  alloc((size_t)E * 4);
    unsigned short* xb = (unsigned short*)alloc((size_t)N * 64 * 2);
    unsigned short* z1 = (unsigned short*)alloc((size_t)N * 64 * 2);
    // pairs dead after k_bucket; z2 born at 2nd k_prop — share storage
    char* uni = alloc((size_t)E * 8 > (size_t)N * 64 * 2 ? (size_t)E * 8 : (size_t)N * 64 * 2);
    int2* pairs = (int2*)uni;
    unsigned short* z2 = (unsigned short*)uni;

    hipMemsetAsync(bhist, 0, (size_t)NB * 4, stream);

    int pe = (E + EPB - 1) / EPB;          // 391 partition blocks
    k_bhist<<<pe, 256, 0, stream>>>(ei + E, E, bhist, NB);
    k_bscan<<<1, MAXNB, 0, stream>>>(bhist, bbase, gcur, NB);
    k_part<<<pe, 256, 0, stream>>>(ei, E, gcur, pairs, NB);
    k_bucket<<<NB, TPBK, 0, stream>>>(pairs, bbase, bhist, rows, cnt, offs, dis, x, xb, N);

    int pb = (int)(((size_t)N * 64 + 255) / 256);
    k_prop<<<pb, 256, 0, stream>>>(xb, z1, dis, offs, cnt, rows, N);
    k_prop<<<pb, 256, 0, stream>>>(z1, z2, dis, offs, cnt, rows, N);

    k_head<<<(N + 255) / 256, 256, 0, stream>>>(z2, cnt, W, b, out, N);
}

// Round 5
// 163.683 us; speedup vs baseline: 3.6851x; 1.1448x over previous
//
#include <hip/hip_runtime.h>
#include <math.h>

#define NFEAT 50
#define NCLS 40
#define TPBK 256          // targets per bucket (power of 2)
#define TPBK_SHIFT 8
#define EPB 4096          // edges per partition/bucket block
#define MAXNB 512         // max buckets supported by single-block scan

__device__ __forceinline__ float bf2f(unsigned short u) {
    return __uint_as_float(((unsigned)u) << 16);
}
__device__ __forceinline__ unsigned short f2bf(float f) {
    unsigned u = __float_as_uint(f);
    unsigned r = (u + 0x7FFFu + ((u >> 16) & 1u)) >> 16;   // round-nearest-even
    return (unsigned short)r;
}

// ---- 1. bucket histogram over targets (1024 thr, 4 edges each) ------------

__global__ __launch_bounds__(1024) void k_bhist(const int* __restrict__ col, int E,
                                                int* __restrict__ bhist, int NB) {
    __shared__ int h[MAXNB];
    for (int i = threadIdx.x; i < NB; i += 1024) h[i] = 0;
    __syncthreads();
    int i0 = blockIdx.x * EPB;
    #pragma unroll
    for (int k = 0; k < EPB / 1024; k++) {
        int e = i0 + k * 1024 + threadIdx.x;
        if (e < E) atomicAdd(&h[col[e] >> TPBK_SHIFT], 1);
    }
    __syncthreads();
    for (int i = threadIdx.x; i < NB; i += 1024)
        if (h[i]) atomicAdd(&bhist[i], h[i]);
}

// ---- 2. scan bucket bases (single block) ----------------------------------

__global__ void k_bscan(const int* __restrict__ bhist, int* __restrict__ bbase,
                        int* __restrict__ gcur, int NB) {
    __shared__ int s[MAXNB];
    int t = threadIdx.x;
    int v = (t < NB) ? bhist[t] : 0;
    s[t] = v;
    __syncthreads();
    for (int off = 1; off < MAXNB; off <<= 1) {
        int a = (t >= off) ? s[t - off] : 0;
        __syncthreads();
        s[t] += a;
        __syncthreads();
    }
    if (t < NB) { int b = s[t] - v; bbase[t] = b; gcur[t] = b; }
}

// ---- 3. partition edges into bucket-contiguous (r,c) pairs ----------------

__global__ __launch_bounds__(1024) void k_part(const int* __restrict__ ei, int E,
                                               int* __restrict__ gcur,
                                               int2* __restrict__ pairs, int NB) {
    __shared__ int h[MAXNB];
    __shared__ int base[MAXNB];
    int t = threadIdx.x;
    for (int i = t; i < NB; i += 1024) h[i] = 0;
    __syncthreads();
    int i0 = blockIdx.x * EPB;
    int r[EPB / 1024], c[EPB / 1024];
    #pragma unroll
    for (int k = 0; k < EPB / 1024; k++) {
        int e = i0 + k * 1024 + t;
        if (e < E) {
            r[k] = ei[e];
            c[k] = ei[E + e];
            atomicAdd(&h[c[k] >> TPBK_SHIFT], 1);
        } else c[k] = -1;
    }
    __syncthreads();
    for (int i = t; i < NB; i += 1024)
        base[i] = h[i] ? atomicAdd(&gcur[i], h[i]) : 0;
    __syncthreads();
    for (int i = t; i < NB; i += 1024) h[i] = 0;
    __syncthreads();
    #pragma unroll
    for (int k = 0; k < EPB / 1024; k++) {
        if (c[k] >= 0) {
            int bkt = c[k] >> TPBK_SHIFT;
            int p = base[bkt] + atomicAdd(&h[bkt], 1);
            pairs[p] = make_int2(r[k], c[k]);
        }
    }
}

// ---- 4. per-bucket CSR finalize + fused x->z0 conversion (1024 thr) -------

__global__ __launch_bounds__(1024) void k_bucket(const int2* __restrict__ pairs,
                         const int* __restrict__ bbase,
                         const int* __restrict__ bhist, int* __restrict__ rows,
                         int* __restrict__ cnt, int* __restrict__ offs,
                         float* __restrict__ dis, const float* __restrict__ x,
                         unsigned short* __restrict__ xb, int N) {
    int b = blockIdx.x;
    int ebeg = bbase[b], m = bhist[b];
    int t0 = b << TPBK_SHIFT;
    __shared__ int h[TPBK];
    __shared__ int off[TPBK];
    __shared__ float diss[TPBK];
    __shared__ int wtot[4];
    int t = threadIdx.x;       // 1024 threads
    if (t < TPBK) h[t] = 0;
    __syncthreads();

    // histogram + register-cache pairs (first 4096; remainder re-read later)
    int2 pc[4]; bool ok[4];
    #pragma unroll
    for (int k = 0; k < 4; k++) {
        int i = t + k * 1024;
        ok[k] = i < m;
        if (ok[k]) {
            pc[k] = pairs[ebeg + i];
            atomicAdd(&h[pc[k].y - t0], 1);
        }
    }
    for (int i = 4096 + t; i < m; i += 1024)
        atomicAdd(&h[pairs[ebeg + i].y - t0], 1);
    __syncthreads();

    // exclusive scan of h[256] via wave shuffles (threads 0..255 = 4 waves)
    int v = 0, incl = 0;
    if (t < TPBK) {
        v = h[t];
        h[t] = 0;                      // reset for scatter pass
        incl = v;
        int l = t & 63;
        #pragma unroll
        for (int d = 1; d < 64; d <<= 1) {
            int tmp = __shfl_up(incl, d);
            if (l >= d) incl += tmp;
        }
        if (l == 63) wtot[t >> 6] = incl;
    }
    __syncthreads();
    if (t < TPBK) {
        int pre = 0;
        #pragma unroll
        for (int w = 0; w < 3; w++) if ((t >> 6) > w) pre += wtot[w];
        int excl = pre + incl - v;
        off[t] = excl;
        int tg = t0 + t;
        float d = rsqrtf((float)(v + 1));
        diss[t] = d;
        if (tg < N) {
            cnt[tg] = v;
            offs[tg] = ebeg + excl;
            dis[tg] = d;
        }
    }
    __syncthreads();

    // scatter into rows (order within target irrelevant)
    #pragma unroll
    for (int k = 0; k < 4; k++) {
        if (ok[k]) {
            int lt = pc[k].y - t0;
            int pos = off[lt] + atomicAdd(&h[lt], 1);
            rows[ebeg + pos] = pc[k].x;
        }
    }
    for (int i = 4096 + t; i < m; i += 1024) {
        int2 p = pairs[ebeg + i];
        int lt = p.y - t0;
        int pos = off[lt] + atomicAdd(&h[lt], 1);
        rows[ebeg + pos] = p.x;
    }

    // fused conversion: xb[n] = f2bf(dis[n] * x[n]) for this block's 256 nodes
    int nmax = N - t0; if (nmax > TPBK) nmax = TPBK;
    for (int idx = t; idx < (nmax << 6); idx += 1024) {
        int nl = idx >> 6, f = idx & 63;
        int n = t0 + nl;
        float val = (f < NFEAT) ? x[(size_t)n * NFEAT + f] * diss[nl] : 0.f;
        xb[((size_t)n << 6) + f] = f2bf(val);
    }
}

// ---- 5. propagation: z_out[c] = dis[c]^2 * (z[c] + sum z[r]) --------------
// wave per target; 4 lane-groups of 16; each lane carries 4 features (ushort4).

__global__ void k_prop(const unsigned short* __restrict__ zin, unsigned short* __restrict__ zout,
                       const float* __restrict__ dis, const int* __restrict__ offs,
                       const int* __restrict__ cnt, const int* __restrict__ rows, int N) {
    int wid = (blockIdx.x * blockDim.x + threadIdx.x) >> 6;
    int lane = threadIdx.x & 63;
    if (wid >= N) return;
    int g = lane >> 4;            // edge subgroup 0..3
    int fl = (lane & 15) << 2;    // feature base 0,4,...,60
    int beg = offs[wid], num = cnt[wid];

    float a0 = 0.f, a1 = 0.f, a2 = 0.f, a3 = 0.f;
    if (g == 0) {                 // self-loop term counted once
        ushort4 s = *(const ushort4*)&zin[((size_t)wid << 6) + fl];
        a0 = bf2f(s.x); a1 = bf2f(s.y); a2 = bf2f(s.z); a3 = bf2f(s.w);
    }

    for (int j = 0; j < num; j += 16) {
        int i0 = j + (g << 2);
        int e0 = i0, e1 = i0 + 1, e2 = i0 + 2, e3 = i0 + 3;
        float m0 = e0 < num ? 1.f : 0.f;
        float m1 = e1 < num ? 1.f : 0.f;
        float m2 = e2 < num ? 1.f : 0.f;
        float m3 = e3 < num ? 1.f : 0.f;
        int c0 = e0 < num ? e0 : num - 1;
        int c1 = e1 < num ? e1 : num - 1;
        int c2 = e2 < num ? e2 : num - 1;
        int c3 = e3 < num ? e3 : num - 1;
        int r0 = rows[beg + c0];
        int r1 = rows[beg + c1];
        int r2 = rows[beg + c2];
        int r3 = rows[beg + c3];
        ushort4 v0 = *(const ushort4*)&zin[((size_t)r0 << 6) + fl];
        ushort4 v1 = *(const ushort4*)&zin[((size_t)r1 << 6) + fl];
        ushort4 v2 = *(const ushort4*)&zin[((size_t)r2 << 6) + fl];
        ushort4 v3 = *(const ushort4*)&zin[((size_t)r3 << 6) + fl];
        a0 = fmaf(m0, bf2f(v0.x), a0); a1 = fmaf(m0, bf2f(v0.y), a1);
        a2 = fmaf(m0, bf2f(v0.z), a2); a3 = fmaf(m0, bf2f(v0.w), a3);
        a0 = fmaf(m1, bf2f(v1.x), a0); a1 = fmaf(m1, bf2f(v1.y), a1);
        a2 = fmaf(m1, bf2f(v1.z), a2); a3 = fmaf(m1, bf2f(v1.w), a3);
        a0 = fmaf(m2, bf2f(v2.x), a0); a1 = fmaf(m2, bf2f(v2.y), a1);
        a2 = fmaf(m2, bf2f(v2.z), a2); a3 = fmaf(m2, bf2f(v2.w), a3);
        a0 = fmaf(m3, bf2f(v3.x), a0); a1 = fmaf(m3, bf2f(v3.y), a1);
        a2 = fmaf(m3, bf2f(v3.z), a2); a3 = fmaf(m3, bf2f(v3.w), a3);
    }

    a0 += __shfl_xor(a0, 16); a0 += __shfl_xor(a0, 32);
    a1 += __shfl_xor(a1, 16); a1 += __shfl_xor(a1, 32);
    a2 += __shfl_xor(a2, 16); a2 += __shfl_xor(a2, 32);
    a3 += __shfl_xor(a3, 16); a3 += __shfl_xor(a3, 32);

    float dn = dis[wid];
    float s2 = dn * dn;
    if (lane < 16) {
        ushort4 o;
        o.x = f2bf(a0 * s2); o.y = f2bf(a1 * s2);
        o.z = f2bf(a2 * s2); o.w = f2bf(a3 * s2);
        *(ushort4*)&zout[((size_t)wid << 6) + fl] = o;
    }
}

// ---- 6. head: h = z / dis; logits = h @ W + b; log_softmax ----------------

__global__ void k_head(const unsigned short* __restrict__ z2, const int* __restrict__ cnt,
                       const float* __restrict__ W, const float* __restrict__ b,
                       float* __restrict__ out, int N) {
    int n = blockIdx.x * blockDim.x + threadIdx.x;
    if (n >= N) return;
    float s = sqrtf((float)(cnt[n] + 1));   // 1/dis
    float acc[NCLS];
    #pragma unroll
    for (int c = 0; c < NCLS; c++) acc[c] = b[c];
    for (int k = 0; k < NFEAT; k++) {
        float hk = bf2f(z2[((size_t)n << 6) + k]) * s;
        #pragma unroll
        for (int c = 0; c < NCLS; c++) acc[c] += hk * W[k * NCLS + c];
    }
    float m = acc[0];
    #pragma unroll
    for (int c = 1; c < NCLS; c++) m = fmaxf(m, acc[c]);
    float sum = 0.f;
    #pragma unroll
    for (int c = 0; c < NCLS; c++) sum += __expf(acc[c] - m);
    float l = __logf(sum) + m;
    #pragma unroll
    for (int c = 0; c < NCLS; c++) out[(size_t)n * NCLS + c] = acc[c] - l;
}

// ---- launcher -------------------------------------------------------------

extern "C" void kernel_launch(void* const* d_in, const int* in_sizes, int n_in,
                              void* d_out, int out_size, void* d_ws, size_t ws_size,
                              hipStream_t stream) {
    const float* x = (const float*)d_in[0];
    const int* ei = (const int*)d_in[1];   // [2, E] int32
    const float* W = (const float*)d_in[2];
    const float* b = (const float*)d_in[3];
    float* out = (float*)d_out;

    int N = in_sizes[0] / NFEAT;
    int E = in_sizes[1] / 2;
    int NB = (N + TPBK - 1) / TPBK;        // 391 buckets

    char* w = (char*)d_ws;
    auto alloc = [&](size_t bytes) { char* p = w; w += (bytes + 255) & ~(size_t)255; return p; };
    int*   bhist = (int*)  alloc((size_t)NB * 4);
    int*   bbase = (int*)  alloc((size_t)NB * 4);
    int*   gcur  = (int*)  alloc((size_t)NB * 4);
    int*   cnt   = (int*)  alloc((size_t)N * 4);
    int*   offs  = (int*)  alloc((size_t)N * 4);
    float* dis   = (float*)alloc((size_t)N * 4);
    int*   rows  = (int*)  alloc((size_t)E * 4);
    unsigned short* xb = (unsigned short*)alloc((size_t)N * 64 * 2);
    unsigned short* z1 = (unsigned short*)alloc((size_t)N * 64 * 2);
    // pairs dead after k_bucket; z2 born at 2nd k_prop — share storage
    char* uni = alloc((size_t)E * 8 > (size_t)N * 64 * 2 ? (size_t)E * 8 : (size_t)N * 64 * 2);
    int2* pairs = (int2*)uni;
    unsigned short* z2 = (unsigned short*)uni;

    hipMemsetAsync(bhist, 0, (size_t)NB * 4, stream);

    int pe = (E + EPB - 1) / EPB;          // 391 blocks
    k_bhist<<<pe, 1024, 0, stream>>>(ei + E, E, bhist, NB);
    k_bscan<<<1, MAXNB, 0, stream>>>(bhist, bbase, gcur, NB);
    k_part<<<pe, 1024, 0, stream>>>(ei, E, gcur, pairs, NB);
    k_bucket<<<NB, 1024, 0, stream>>>(pairs, bbase, bhist, rows, cnt, offs, dis, x, xb, N);

    int pb = (int)(((size_t)N * 64 + 255) / 256);
    k_prop<<<pb, 256, 0, stream>>>(xb, z1, dis, offs, cnt, rows, N);
    k_prop<<<pb, 256, 0, stream>>>(z1, z2, dis, offs, cnt, rows, N);

    k_head<<<(N + 255) / 256, 256, 0, stream>>>(z2, cnt, W, b, out, N);
}